// Round 4
// baseline (195.602 us; speedup 1.0000x reference)
//
#include <hip/hip_runtime.h>
#include <hip/hip_bf16.h>

// TreeLoss: hierarchical softmax-style loss over a fixed 2-level tree.
// States: 1 empty + 24 coarse-only + 1000 (coarse,fine) pairs.
// z = 1 + sum_c e_c + sum_{n>=24} e_{n%24} * e_n
// marginal(label<24=c)  = e_c * (1 + sum_{n≡c (24), n>=24} e_n)
// marginal(label>=24)   = e_{label%24} * e_label
// out = mean(log z - log marginal)
//
// R1: two-stage reduction replaced 8192 same-address atomics (−68 us).
// R2: loop stripped to mul+exp+ds_read+fma — NEUTRAL (−2 us): kernel is not
//     VALU-bound. Diagnosis: 8192 short-lived blocks, __syncthreads drains
//     vmcnt(0), serial lane-0 tail, block churn → load pipe idles.
// R3: persistent pipelined waves. 1024 blocks (4/CU), 8 rows/wave with
//     double-buffered prefetch; coarse table via __shfl (bpermute) instead of
//     LDS so the hot loop has ZERO barriers; __shfl_xor butterfly (all lanes
//     hold totals, no divergent tail). ~144 us of reported dur is fixed
//     harness restore/poison (512 MiB ws fill at ~77 us tops the profile).

constexpr int N_COARSE = 24;
constexpr int TOTAL = 1024;          // columns per row
constexpr int BATCH = 32768;
constexpr int WPB = 4;               // waves per block (256 threads)
constexpr int GRID1 = 1024;          // 4 blocks/CU — persistent
constexpr int NWAVES = GRID1 * WPB;  // 4096
constexpr int RPW = BATCH / NWAVES;  // 8 rows per wave

__global__ __launch_bounds__(256) void treeloss_partial(
    const float* __restrict__ fs, const int* __restrict__ labels,
    float* __restrict__ partials) {
  const int wave = threadIdx.x >> 6;
  const int lane = threadIdx.x & 63;
  const int w = blockIdx.x * WPB + wave;
  const int b0 = w * RPW;

  // Lane-fixed shuffle indices: element n -> coarse c = n % 24.
  // n = j*256 + 4*lane + k; 256%24=16, 512%24=8, 768%24=0.
  const int cbase = (lane * 4) % N_COARSE;         // {0,4,...,20}
  int idx1[4], idx2[4];                            // j=1, j=2 (j=0,3: cbase+k)
#pragma unroll
  for (int k = 0; k < 4; ++k) {
    const int t1 = cbase + 16 + k; idx1[k] = (t1 >= N_COARSE) ? t1 - N_COARSE : t1;
    const int t2 = cbase + 8 + k;  idx2[k] = (t2 >= N_COARSE) ? t2 - N_COARSE : t2;
  }

  float4 buf[2][4];   // double-buffered row (16 floats/lane per row)
  float  cbuf[2];     // row[lane] for lanes<24 (coarse values)
  int    lbuf[2];     // label

  {  // prefetch row 0
    const float* r = fs + (size_t)b0 * TOTAL;
    const float4* r4 = reinterpret_cast<const float4*>(r);
    buf[0][0] = r4[lane];       buf[0][1] = r4[lane + 64];
    buf[0][2] = r4[lane + 128]; buf[0][3] = r4[lane + 192];
    cbuf[0] = (lane < N_COARSE) ? r[lane] : 0.0f;
    lbuf[0] = labels[b0];
  }

  float loss = 0.0f;
#pragma unroll
  for (int rr = 0; rr < RPW; ++rr) {
    const int cur = rr & 1, nxt = cur ^ 1;
    if (rr + 1 < RPW) {  // prefetch next row while computing current
      const float* r = fs + (size_t)(b0 + rr + 1) * TOTAL;
      const float4* r4 = reinterpret_cast<const float4*>(r);
      buf[nxt][0] = r4[lane];       buf[nxt][1] = r4[lane + 64];
      buf[nxt][2] = r4[lane + 128]; buf[nxt][3] = r4[lane + 192];
      cbuf[nxt] = (lane < N_COARSE) ? r[lane] : 0.0f;
      lbuf[nxt] = labels[b0 + rr + 1];
    }

    const float ec = __expf(cbuf[cur]);  // e_c in lanes 0..23
    const int label = lbuf[cur];
    const float* row = fs + (size_t)(b0 + rr) * TOTAL;

    float zp = 0.0f;  // partial of (z - 1)
    {  // j = 0: lanes 0..5 hold the 24 coarse-only states (mult = 1)
      const float4 v = buf[cur][0];
      const float vv[4] = {v.x, v.y, v.z, v.w};
#pragma unroll
      for (int k = 0; k < 4; ++k) {
        float mult = __shfl(ec, cbase + k);
        if (lane < 6) mult = 1.0f;
        zp += mult * __expf(vv[k]);
      }
    }
    {
      const float4 v = buf[cur][1];
      const float vv[4] = {v.x, v.y, v.z, v.w};
#pragma unroll
      for (int k = 0; k < 4; ++k) zp += __shfl(ec, idx1[k]) * __expf(vv[k]);
    }
    {
      const float4 v = buf[cur][2];
      const float vv[4] = {v.x, v.y, v.z, v.w};
#pragma unroll
      for (int k = 0; k < 4; ++k) zp += __shfl(ec, idx2[k]) * __expf(vv[k]);
    }
    {
      const float4 v = buf[cur][3];
      const float vv[4] = {v.x, v.y, v.z, v.w};
#pragma unroll
      for (int k = 0; k < 4; ++k) zp += __shfl(ec, cbase + k) * __expf(vv[k]);
    }

    // Marginal. label<24 (~2.3% of rows, wave-uniform branch): gather the
    // <=42 fine nodes ≡ label (mod 24); loads hit L1 (row just streamed).
    float g = 0.0f;
    const bool coarse_label = (label < N_COARSE);
    if (coarse_label) {
      const int gi = label + N_COARSE * (lane + 1);
      if (gi < TOTAL) g = __expf(row[gi]);
    }

#pragma unroll
    for (int off = 32; off > 0; off >>= 1) {  // xor-butterfly: totals in all lanes
      zp += __shfl_xor(zp, off);
      g  += __shfl_xor(g, off);
    }

    const int c_eff = coarse_label ? label : (label % N_COARSE);
    const float el = __shfl(ec, c_eff);
    const float m = coarse_label ? el * (1.0f + g) : el * __expf(row[label]);
    loss += __logf(1.0f + zp) - __logf(m);
  }

  if (lane == 0) partials[w] = loss;
}

__global__ __launch_bounds__(1024) void treeloss_reduce(
    const float* __restrict__ partials, float* __restrict__ out) {
  const int tid = threadIdx.x;
  const int lane = tid & 63;
  const int wv = tid >> 6;
  const float4 a = reinterpret_cast<const float4*>(partials)[tid];  // 4096 floats
  float s = (a.x + a.y) + (a.z + a.w);
#pragma unroll
  for (int off = 32; off > 0; off >>= 1) s += __shfl_xor(s, off);
  __shared__ float ps[16];
  if (lane == 0) ps[wv] = s;
  __syncthreads();
  if (tid == 0) {
    float t = 0.0f;
#pragma unroll
    for (int k = 0; k < 16; ++k) t += ps[k];
    out[0] = t * (1.0f / (float)BATCH);
  }
}

extern "C" void kernel_launch(void* const* d_in, const int* in_sizes, int n_in,
                              void* d_out, int out_size, void* d_ws, size_t ws_size,
                              hipStream_t stream) {
  const float* fs = (const float*)d_in[0];
  const int* labels = (const int*)d_in[1];
  // d_in[2] (stateSpace) is deterministic structure; hardcoded in the kernel.
  float* out = (float*)d_out;
  float* partials = (float*)d_ws;  // 4096 floats = 16 KiB scratch

  treeloss_partial<<<GRID1, 256, 0, stream>>>(fs, labels, partials);
  treeloss_reduce<<<1, 1024, 0, stream>>>(partials, out);
}

// Round 5
// 193.752 us; speedup vs baseline: 1.0095x; 1.0095x over previous
//
#include <hip/hip_runtime.h>
#include <hip/hip_bf16.h>

// TreeLoss: hierarchical softmax-style loss over a fixed 2-level tree.
// States: 1 empty + 24 coarse-only + 1000 (coarse,fine) pairs.
// z = 1 + sum_c e_c + sum_{n>=24} e_{n%24} * e_n
// marginal(label<24=c)  = e_c * (1 + sum_{n≡c (24), n>=24} e_n)
// marginal(label>=24)   = e_{label%24} * e_label
// out = mean(log z - log marginal)
//
// R1: two-stage reduction replaced 8192 same-address atomics (−68 us).
// R2: VALU-stripped loop — NEUTRAL (−2 us): not VALU-bound.
// R3: persistent 16-waves/CU pipelined — REGRESSED (+6 us): occupancy cut
//     hurt; per-wave latency hiding is not the problem.
// R4: throughput-streaming shape. 2 rows/wave with ALL loads (8x float4 +
//     coarse + labels + row[label]) issued before any compute (~8 KiB MLP
//     per wave); ZERO LDS / ZERO barriers in the partial kernel (coarse
//     mults via register shuffle, marginal via pre-issued row[label] load
//     — kills the serial end-of-row dependent load); 4096x256 grid for a
//     deep dispatch queue and max resident waves. ~144 us of reported dur
//     is fixed harness restore/poison (512 MiB ws fills at ~77 us).

constexpr int N_COARSE = 24;
constexpr int TOTAL = 1024;            // columns per row
constexpr int BATCH = 32768;
constexpr int RPW = 2;                 // rows per wave
constexpr int NWAVES = BATCH / RPW;    // 16384
constexpr int TPB = 256;               // 4 waves/block
constexpr int GRID1 = NWAVES / (TPB / 64);  // 4096 blocks

__global__ __launch_bounds__(TPB, 4) void treeloss_partial(
    const float* __restrict__ fs, const int* __restrict__ labels,
    float* __restrict__ partials) {
  const int wave = threadIdx.x >> 6;
  const int lane = threadIdx.x & 63;
  const int w = blockIdx.x * (TPB / 64) + wave;
  const int b0 = w * RPW;

  const float* __restrict__ rowA = fs + (size_t)b0 * TOTAL;
  const float* __restrict__ rowB = rowA + TOTAL;
  const float4* __restrict__ a4 = reinterpret_cast<const float4*>(rowA);
  const float4* __restrict__ c4 = reinterpret_cast<const float4*>(rowB);

  // ---- issue EVERYTHING up-front: 8x1KiB row loads + labels + coarse ----
  const float4 a0 = a4[lane], a1 = a4[lane + 64], a2 = a4[lane + 128], a3 = a4[lane + 192];
  const float4 b0v = c4[lane], b1 = c4[lane + 64], b2 = c4[lane + 128], b3 = c4[lane + 192];
  const float cA = (lane < N_COARSE) ? rowA[lane] : 0.0f;
  const float cB = (lane < N_COARSE) ? rowB[lane] : 0.0f;
  const int labA = labels[b0];
  const int labB = labels[b0 + 1];
  const float lvA = rowA[labA];   // pre-issued; used only when labA>=24
  const float lvB = rowB[labB];

  // Lane-fixed shuffle indices: element n -> coarse c = n % 24.
  // n = j*256 + 4*lane + k; 256%24=16, 512%24=8, 768%24=0.
  const int cbase = (lane * 4) % N_COARSE;   // {0,4,...,20}
  int i1[4], i2[4];
#pragma unroll
  for (int k = 0; k < 4; ++k) {
    const int t1 = cbase + 16 + k; i1[k] = (t1 >= N_COARSE) ? t1 - N_COARSE : t1;
    const int t2 = cbase + 8 + k;  i2[k] = (t2 >= N_COARSE) ? t2 - N_COARSE : t2;
  }

  const float ecA = __expf(cA);   // e_c in lanes 0..23
  const float ecB = __expf(cB);

  float zpA = 0.0f, zpB = 0.0f;   // partials of (z - 1); independent chains
  {  // j = 0: lanes 0..5 hold the 24 coarse-only states (mult = 1)
    const float avv[4] = {a0.x, a0.y, a0.z, a0.w};
    const float bvv[4] = {b0v.x, b0v.y, b0v.z, b0v.w};
#pragma unroll
    for (int k = 0; k < 4; ++k) {
      float mA = __shfl(ecA, cbase + k), mB = __shfl(ecB, cbase + k);
      if (lane < 6) { mA = 1.0f; mB = 1.0f; }
      zpA += mA * __expf(avv[k]);
      zpB += mB * __expf(bvv[k]);
    }
  }
  {
    const float avv[4] = {a1.x, a1.y, a1.z, a1.w};
    const float bvv[4] = {b1.x, b1.y, b1.z, b1.w};
#pragma unroll
    for (int k = 0; k < 4; ++k) {
      zpA += __shfl(ecA, i1[k]) * __expf(avv[k]);
      zpB += __shfl(ecB, i1[k]) * __expf(bvv[k]);
    }
  }
  {
    const float avv[4] = {a2.x, a2.y, a2.z, a2.w};
    const float bvv[4] = {b2.x, b2.y, b2.z, b2.w};
#pragma unroll
    for (int k = 0; k < 4; ++k) {
      zpA += __shfl(ecA, i2[k]) * __expf(avv[k]);
      zpB += __shfl(ecB, i2[k]) * __expf(bvv[k]);
    }
  }
  {
    const float avv[4] = {a3.x, a3.y, a3.z, a3.w};
    const float bvv[4] = {b3.x, b3.y, b3.z, b3.w};
#pragma unroll
    for (int k = 0; k < 4; ++k) {
      zpA += __shfl(ecA, cbase + k) * __expf(avv[k]);
      zpB += __shfl(ecB, cbase + k) * __expf(bvv[k]);
    }
  }

#pragma unroll
  for (int off = 32; off > 0; off >>= 1) {  // xor-butterfly: totals in all lanes
    zpA += __shfl_xor(zpA, off);
    zpB += __shfl_xor(zpB, off);
  }

  // Marginals (label is wave-uniform; coarse branch ~2.3% of rows).
  float mA, mB;
  if (labA < N_COARSE) {
    float g = 0.0f;
    const int gi = labA + N_COARSE * (lane + 1);
    if (gi < TOTAL) g = __expf(rowA[gi]);       // L1/L2-hot: row just streamed
#pragma unroll
    for (int off = 32; off > 0; off >>= 1) g += __shfl_xor(g, off);
    mA = __shfl(ecA, labA) * (1.0f + g);
  } else {
    mA = __shfl(ecA, labA % N_COARSE) * __expf(lvA);
  }
  if (labB < N_COARSE) {
    float g = 0.0f;
    const int gi = labB + N_COARSE * (lane + 1);
    if (gi < TOTAL) g = __expf(rowB[gi]);
#pragma unroll
    for (int off = 32; off > 0; off >>= 1) g += __shfl_xor(g, off);
    mB = __shfl(ecB, labB) * (1.0f + g);
  } else {
    mB = __shfl(ecB, labB % N_COARSE) * __expf(lvB);
  }

  if (lane == 0) {
    partials[w] = (__logf(1.0f + zpA) - __logf(mA)) +
                  (__logf(1.0f + zpB) - __logf(mB));
  }
}

__global__ __launch_bounds__(1024) void treeloss_reduce(
    const float* __restrict__ partials, float* __restrict__ out) {
  const int tid = threadIdx.x;
  const int lane = tid & 63;
  const int wv = tid >> 6;
  const float4* __restrict__ p4 = reinterpret_cast<const float4*>(partials);
  float s = 0.0f;
#pragma unroll
  for (int i = 0; i < NWAVES / 4 / 1024; ++i) {  // 16384 floats = 4096 float4
    const float4 a = p4[tid + i * 1024];
    s += (a.x + a.y) + (a.z + a.w);
  }
#pragma unroll
  for (int off = 32; off > 0; off >>= 1) s += __shfl_xor(s, off);
  __shared__ float ps[16];
  if (lane == 0) ps[wv] = s;
  __syncthreads();
  if (tid == 0) {
    float t = 0.0f;
#pragma unroll
    for (int k = 0; k < 16; ++k) t += ps[k];
    out[0] = t * (1.0f / (float)BATCH);
  }
}

extern "C" void kernel_launch(void* const* d_in, const int* in_sizes, int n_in,
                              void* d_out, int out_size, void* d_ws, size_t ws_size,
                              hipStream_t stream) {
  const float* fs = (const float*)d_in[0];
  const int* labels = (const int*)d_in[1];
  // d_in[2] (stateSpace) is deterministic structure; hardcoded in the kernel.
  float* out = (float*)d_out;
  float* partials = (float*)d_ws;  // 16384 floats = 64 KiB scratch

  treeloss_partial<<<GRID1, TPB, 0, stream>>>(fs, labels, partials);
  treeloss_reduce<<<1, 1024, 0, stream>>>(partials, out);
}